// Round 13
// baseline (199.304 us; speedup 1.0000x reference)
//
#include <hip/hip_runtime.h>
#include <hip/hip_bf16.h>
#include <stdint.h>

#define TOKENS 4096
#define DIN 1024
#define DOUT 1024
#define RANK 8
#define TPB 8          // tokens per block

typedef __attribute__((ext_vector_type(4))) float f32x4;
typedef __attribute__((ext_vector_type(8))) short short8;

__device__ __forceinline__ unsigned short f2bf(float f) {
    union { float f; unsigned u; } v; v.f = f;
    unsigned r = v.u + 0x7FFFu + ((v.u >> 16) & 1u);
    return (unsigned short)(r >> 16);
}

__device__ __forceinline__ float dot4(float4 a, float4 b) {
    return a.x * b.x + a.y * b.y + a.z * b.z + a.w * b.w;
}

// W [DOUT][DIN] fp32 -> bf16 (Wb then L2-resident for the fused kernel)
__global__ __launch_bounds__(256) void k_convert_w(const float* __restrict__ W,
                                                   ushort* __restrict__ Wb) {
    int i = blockIdx.x * 256 + threadIdx.x;
    float4 v = ((const float4*)W)[i];
    ushort4 u;
    u.x = f2bf(v.x); u.y = f2bf(v.y); u.z = f2bf(v.z); u.w = f2bf(v.w);
    ((ushort4*)Wb)[i] = u;
}

// Fully fused: per block of 8 tokens —
//  A: x loaded once (fp32 regs) -> bf16 swizzled LDS (MFMA a-frags)
//  B: inter[8][8] = x.B from regs (B streamed once, coalesced); shfl-reduce
//  C: out = bias + x@W^T (bf16 MFMA; W b-frags straight from L2, no staging,
//     no barriers) + inter.A (A streamed once in per-pass epilogues)
// ONE __syncthreads per block. Everything HBM is read exactly once.
__global__ __launch_bounds__(256) void k_fused(const float* __restrict__ x,
                                               const float* __restrict__ Bp,
                                               const float* __restrict__ Ap,
                                               const ushort* __restrict__ Wb,
                                               const float* __restrict__ bias,
                                               float* __restrict__ out) {
    __shared__ ushort xls[16 * DIN];     // 32 KB: 16 rows (8 real + 8 zero pad)
    __shared__ float sInter[TPB * RANK]; // 256 B

    const int tid = threadIdx.x;
    const int lane = tid & 63, wid = tid >> 6;
    const int col16 = lane & 15, kg = lane >> 4;
    const int T0 = blockIdx.x * TPB;

    // ---- Phase A: x -> regs + swizzled bf16 LDS; zero pad rows ----
    float4 xv[2][4];
#pragma unroll
    for (int tt = 0; tt < 2; ++tt) {
        const int tl = wid * 2 + tt;                     // local token 0..7
        const float4* xp = (const float4*)(x + (size_t)(T0 + tl) * DIN);
#pragma unroll
        for (int j = 0; j < 4; ++j) {
            float4 v = xp[j * 64 + lane];
            xv[tt][j] = v;
            ushort4 u;
            u.x = f2bf(v.x); u.y = f2bf(v.y); u.z = f2bf(v.z); u.w = f2bf(v.w);
            const int c = (lane >> 1) + j * 32;          // 16B chunk index
            const int cs = c ^ (tl & 7);                 // T2 XOR swizzle
            *(ushort4*)((char*)xls + tl * 2048 + cs * 16 + (lane & 1) * 8) = u;
        }
    }
    // zero pad rows 8..15 (zeros are swizzle-invariant)
#pragma unroll
    for (int tt = 0; tt < 2; ++tt) {
        const int rp = 8 + wid * 2 + tt;
        ushort4 z = {0, 0, 0, 0};
#pragma unroll
        for (int j = 0; j < 4; ++j)
            *(ushort4*)((char*)xls + rp * 2048 + (j * 64 + lane) * 8) = z;
    }

    // ---- Phase B: inter = x . B (fp32, from regs; B read once) ----
#pragma unroll
    for (int tt = 0; tt < 2; ++tt) {
        const int tl = wid * 2 + tt;
        const float4* bp = (const float4*)(Bp + (size_t)(T0 + tl) * RANK * DIN);
#pragma unroll
        for (int r = 0; r < RANK; ++r) {
            float s = 0.f;
#pragma unroll
            for (int j = 0; j < 4; ++j)
                s += dot4(bp[r * 256 + j * 64 + lane], xv[tt][j]);
#pragma unroll
            for (int off = 32; off > 0; off >>= 1)
                s += __shfl_xor(s, off, 64);
            if (lane == 0) sInter[tl * RANK + r] = s;
        }
    }
    __syncthreads();   // xls + sInter visible to all waves

    // ---- Phase C: MFMA GEMM (W from L2, no staging) + fused epilogue ----
#pragma unroll
    for (int ps = 0; ps < 4; ++ps) {
        const int ob = ps * 256 + wid * 64;              // wave's 64-out base
        f32x4 acc[4] = {};
#pragma unroll
        for (int ks = 0; ks < 32; ++ks) {
            const int cs = (ks * 4 + kg) ^ (col16 & 7);
            short8 af = *(const short8*)(xls + col16 * DIN + cs * 8);
#pragma unroll
            for (int nf = 0; nf < 4; ++nf) {
                short8 bf = *(const short8*)(Wb + (size_t)(ob + nf * 16 + col16) * DIN +
                                             ks * 32 + kg * 8);
                acc[nf] = __builtin_amdgcn_mfma_f32_16x16x32_bf16(af, bf, acc[nf], 0, 0, 0);
            }
        }
        // Epilogue: rows (tokens) = kg*4+rg; only kg<2 are real (8 tokens).
        if (kg < 2) {
#pragma unroll
            for (int nf = 0; nf < 4; ++nf) {
                const int o = ob + nf * 16 + col16;
                const float bb = bias[o];
#pragma unroll
                for (int rg = 0; rg < 4; ++rg) {
                    const int tl = kg * 4 + rg;
                    const float4* ap = (const float4*)(Ap + ((size_t)(T0 + tl) * DOUT + o) * RANK);
                    float4 a0 = ap[0], a1 = ap[1];
                    const float4* iv = (const float4*)(sInter + tl * RANK);
                    float4 i0 = iv[0], i1 = iv[1];
                    float d = dot4(a0, i0) + dot4(a1, i1);
                    out[(size_t)(T0 + tl) * DOUT + o] = acc[nf][rg] + bb + d;
                }
            }
        }
    }
}

extern "C" void kernel_launch(void* const* d_in, const int* in_sizes, int n_in,
                              void* d_out, int out_size, void* d_ws, size_t ws_size,
                              hipStream_t stream) {
    const float* x    = (const float*)d_in[0];
    const float* Ap   = (const float*)d_in[1];
    const float* Bp   = (const float*)d_in[2];
    const float* W    = (const float*)d_in[3];
    const float* bias = (const float*)d_in[4];
    float* out = (float*)d_out;

    // ws: Wb (2 MB bf16 W) only — no other intermediates.
    ushort* Wb = (ushort*)d_ws;

    hipLaunchKernelGGL(k_convert_w, dim3(DOUT * DIN / 1024), dim3(256), 0, stream, W, Wb);
    hipLaunchKernelGGL(k_fused, dim3(TOKENS / TPB), dim3(256), 0, stream,
                       x, Bp, Ap, Wb, bias, out);
}

// Round 14
// 70.203 us; speedup vs baseline: 2.8390x; 2.8390x over previous
//
#include <hip/hip_runtime.h>
#include <hip/hip_bf16.h>
#include <stdint.h>

#define TOKENS 4096
#define DIN 1024
#define DOUT 1024
#define RANK 8
#define BM 128
#define BN 64
#define BK 64

typedef __attribute__((ext_vector_type(4))) float f32x4;
typedef __attribute__((ext_vector_type(8))) short short8;

__device__ __forceinline__ unsigned short f2bf(float f) {
    union { float f; unsigned u; } v; v.f = f;
    unsigned r = v.u + 0x7FFFu + ((v.u >> 16) & 1u);
    return (unsigned short)(r >> 16);
}

// Fused: blocks [0,1024) -> per-WAVE token inter+xb (no barriers, no LDS);
// blocks [1024,1280) -> W fp32->bf16 conversion.  (R11-proven)
__global__ __launch_bounds__(256) void k_inter_cvt(const float* __restrict__ x,
                                                   const float* __restrict__ Bp,
                                                   const float* __restrict__ W,
                                                   float* __restrict__ inter,
                                                   ushort* __restrict__ xb,
                                                   ushort* __restrict__ Wb) {
    const int bid = blockIdx.x;
    const int tid = threadIdx.x;

    if (bid >= 1024) {
        const int b2 = bid - 1024;
        const float4* w4 = (const float4*)(W + (size_t)b2 * 4096);
        ushort4* o4 = (ushort4*)(Wb + (size_t)b2 * 4096);
#pragma unroll
        for (int j = 0; j < 4; ++j) {
            float4 v = w4[j * 256 + tid];
            ushort4 u;
            u.x = f2bf(v.x); u.y = f2bf(v.y); u.z = f2bf(v.z); u.w = f2bf(v.w);
            o4[j * 256 + tid] = u;
        }
        return;
    }

    const int lane = tid & 63, wave = tid >> 6;
    const int t = bid * 4 + wave;

    const float4* x4 = (const float4*)(x + (size_t)t * DIN);
    float4 xv[4];
#pragma unroll
    for (int j = 0; j < 4; ++j) xv[j] = x4[j * 64 + lane];

    ushort4* xb4 = (ushort4*)(xb + (size_t)t * DIN);
#pragma unroll
    for (int j = 0; j < 4; ++j) {
        ushort4 u;
        u.x = f2bf(xv[j].x); u.y = f2bf(xv[j].y);
        u.z = f2bf(xv[j].z); u.w = f2bf(xv[j].w);
        xb4[j * 64 + lane] = u;
    }

    const float4* B4 = (const float4*)(Bp + (size_t)t * RANK * DIN);
    float acc[RANK];
#pragma unroll
    for (int r = 0; r < RANK; ++r) {
        float s = 0.f;
#pragma unroll
        for (int j = 0; j < 4; ++j) {
            float4 bv = B4[r * 256 + j * 64 + lane];
            s += bv.x * xv[j].x + bv.y * xv[j].y + bv.z * xv[j].z + bv.w * xv[j].w;
        }
        acc[r] = s;
    }

#pragma unroll
    for (int r = 0; r < RANK; ++r) {
#pragma unroll
        for (int off = 32; off > 0; off >>= 1)
            acc[r] += __shfl_xor(acc[r], off, 64);
    }

    if (lane == 0) {
        float4 lo, hi;
        lo.x = acc[0]; lo.y = acc[1]; lo.z = acc[2]; lo.w = acc[3];
        hi.x = acc[4]; hi.y = acc[5]; hi.z = acc[6]; hi.w = acc[7];
        float4* ip = (float4*)(inter + (size_t)t * RANK);
        ip[0] = lo; ip[1] = hi;
    }
}

// out[m,o] = bias[o] + Xb@Wb^T (bf16 MFMA) + sum_r inter[m,r]*A[m,o,r]
// R9's order-pinned COUNTED-vmcnt pipeline + R10's T2 LDS XOR-swizzle.
// Regime-gate rationale (guide §5.5): counted vmcnt amortizes the stage
// stall -> LDS-read becomes critical; T2 removes the 16-way ds_read_b128
// conflict -> the pipeline's gain becomes visible. Each alone was null.
__global__ __launch_bounds__(256, 2) void k_gemm_fused(const ushort* __restrict__ Xb,
                                                       const ushort* __restrict__ Wb,
                                                       const float* __restrict__ bias,
                                                       const float* __restrict__ inter,
                                                       const float* __restrict__ Ap,
                                                       float* __restrict__ out) {
    __shared__ ushort As[2][BM * BK];   // 2 x 16 KB
    __shared__ ushort Bs[2][BN * BK];   // 2 x 8 KB
    __shared__ float sInter[BM * 8];    // 4 KB
    __shared__ float sBias[BN];

    const int tid = threadIdx.x;
    const int lane = tid & 63, wave = tid >> 6;
    const int wm = wave >> 1, wn = wave & 1;

    // XCD-aware bijective swizzle (512 % 8 == 0).
    const int bid = blockIdx.x;
    const int swz = (bid & 7) * 64 + (bid >> 3);
    const int M0 = (swz >> 4) * BM;
    const int N0 = (swz & 15) * BN;

    const int col16 = lane & 15;
    const int kg = lane >> 4;
    const int c8 = col16 & 7;

    ((float4*)sInter)[tid] = ((const float4*)(inter + (size_t)M0 * RANK))[tid];
    if (tid < 16) ((float4*)sBias)[tid] = ((const float4*)(bias + N0))[tid];

    const float* Abase = Ap + ((size_t)(M0 + wm * 64 + kg * 4) * DOUT +
                               (N0 + wn * 32 + col16)) * RANK;

    auto stage = [&](int b, int kt) {
#pragma unroll
        for (int st = 0; st < 4; ++st) {
            int flat = st * 256 + tid;           // 128 rows x 8 chunks of 16B
            int row = flat >> 3, ch = flat & 7;
            int chs = ch ^ (row & 7);            // T2: inverse-swizzled source
            const ushort* g = Xb + (size_t)(M0 + row) * DIN + kt + chs * 8;
            __builtin_amdgcn_global_load_lds(
                (const __attribute__((address_space(1))) void*)g,
                (__attribute__((address_space(3))) void*)(&As[b][flat * 8]), 16, 0, 0);
        }
#pragma unroll
        for (int st = 0; st < 2; ++st) {
            int flat = st * 256 + tid;           // 64 rows x 8 chunks
            int row = flat >> 3, ch = flat & 7;
            int chs = ch ^ (row & 7);
            const ushort* g = Wb + (size_t)(N0 + row) * DIN + kt + chs * 8;
            __builtin_amdgcn_global_load_lds(
                (const __attribute__((address_space(1))) void*)g,
                (__attribute__((address_space(3))) void*)(&Bs[b][flat * 8]), 16, 0, 0);
        }
    };

    // A-row base for iter e (elements 2e, 2e+1).
    auto aptr = [&](int e) {
        const int nf = e >> 3, mf = (e >> 1) & 3, rg0 = (e & 1) * 2;
        return Abase + ((size_t)(mf * 16 + rg0) * DOUT + nf * 16) * RANK;
    };

    float4 areg[2][4];

    // Prologue: A(0) FIRST, then stage(0) — order pinned.
    {
        const float* Ae0 = aptr(0);
        areg[0][0] = ((const float4*)Ae0)[0];
        areg[0][1] = ((const float4*)Ae0)[1];
        areg[0][2] = ((const float4*)(Ae0 + (size_t)DOUT * RANK))[0];
        areg[0][3] = ((const float4*)(Ae0 + (size_t)DOUT * RANK))[1];
    }
    __builtin_amdgcn_sched_barrier(0);
    stage(0, 0);

    f32x4 acc[4][2] = {};

#pragma unroll
    for (int t = 0; t < 16; ++t) {
        const int cur = t & 1;

        if (t < 15) {
            // A(t+1) first...
            const float* Ae0 = aptr(t + 1);
            areg[cur ^ 1][0] = ((const float4*)Ae0)[0];
            areg[cur ^ 1][1] = ((const float4*)Ae0)[1];
            areg[cur ^ 1][2] = ((const float4*)(Ae0 + (size_t)DOUT * RANK))[0];
            areg[cur ^ 1][3] = ((const float4*)(Ae0 + (size_t)DOUT * RANK))[1];
            __builtin_amdgcn_sched_barrier(0);
            // ...then stage(t+1). Outstanding: [A(t)4, stage(t)6, A(t+1)4, stage(t+1)6].
            stage(cur ^ 1, (t + 1) * BK);
        }

        if (t == 0) {
            asm volatile("s_waitcnt vmcnt(10) lgkmcnt(0)" ::: "memory");
        } else if (t < 15) {
            asm volatile("s_waitcnt vmcnt(10)" ::: "memory");
        } else {
            asm volatile("s_waitcnt vmcnt(0)" ::: "memory");
        }
        __builtin_amdgcn_s_barrier();

        // MFMA on buf[cur] — T2-swizzled ds_read offsets (conflict-free).
#pragma unroll
        for (int ks = 0; ks < 2; ++ks) {
            short8 a[4], b[2];
#pragma unroll
            for (int m4 = 0; m4 < 4; ++m4) {
                const int chs = (ks * 4 + kg) ^ c8;
                a[m4] = *(const short8*)(&As[cur][(wm * 64 + m4 * 16 + col16) * BK + chs * 8]);
            }
#pragma unroll
            for (int n2 = 0; n2 < 2; ++n2) {
                const int chs = (ks * 4 + kg) ^ c8;
                b[n2] = *(const short8*)(&Bs[cur][(wn * 32 + n2 * 16 + col16) * BK + chs * 8]);
            }
#pragma unroll
            for (int m4 = 0; m4 < 4; ++m4)
#pragma unroll
                for (int n2 = 0; n2 < 2; ++n2)
                    acc[m4][n2] = __builtin_amdgcn_mfma_f32_16x16x32_bf16(
                        a[m4], b[n2], acc[m4][n2], 0, 0, 0);
        }

        // Adaptation dot (areg[cur] retired by the counted wait above).
        {
            const int nf = t >> 3, mf = (t >> 1) & 3, rg0 = (t & 1) * 2;
            const int mloc0 = wm * 64 + mf * 16 + kg * 4 + rg0;
            const float4* iv0 = (const float4*)(sInter + mloc0 * 8);
            const float4* iv1 = (const float4*)(sInter + (mloc0 + 1) * 8);
            float4 i00 = iv0[0], i01 = iv0[1], i10 = iv1[0], i11 = iv1[1];
            float4 a00 = areg[cur][0], a01 = areg[cur][1];
            float4 a10 = areg[cur][2], a11 = areg[cur][3];
            float d0 = a00.x * i00.x + a00.y * i00.y + a00.z * i00.z + a00.w * i00.w +
                       a01.x * i01.x + a01.y * i01.y + a01.z * i01.z + a01.w * i01.w;
            float d1 = a10.x * i10.x + a10.y * i10.y + a10.z * i10.z + a10.w * i10.w +
                       a11.x * i11.x + a11.y * i11.y + a11.z * i11.z + a11.w * i11.w;
            acc[mf][nf][rg0] += d0;
            acc[mf][nf][rg0 + 1] += d1;
        }

        // Protect buf[cur] from next stage overwrite. Pure exec sync, no drain.
        __builtin_amdgcn_s_barrier();
    }

    // Epilogue: single write of out.
#pragma unroll
    for (int nf = 0; nf < 2; ++nf) {
        const int oc = wn * 32 + nf * 16 + col16;
        const int o = N0 + oc;
        const float bb = sBias[oc];
#pragma unroll
        for (int mf = 0; mf < 4; ++mf) {
#pragma unroll
            for (int rg = 0; rg < 4; ++rg) {
                const int m = M0 + wm * 64 + mf * 16 + kg * 4 + rg;
                out[(size_t)m * DOUT + o] = acc[mf][nf][rg] + bb;
            }
        }
    }
}

extern "C" void kernel_launch(void* const* d_in, const int* in_sizes, int n_in,
                              void* d_out, int out_size, void* d_ws, size_t ws_size,
                              hipStream_t stream) {
    const float* x    = (const float*)d_in[0];
    const float* Ap   = (const float*)d_in[1];
    const float* Bp   = (const float*)d_in[2];
    const float* W    = (const float*)d_in[3];
    const float* bias = (const float*)d_in[4];
    float* out = (float*)d_out;

    // ws: xb (8 MB) | Wb (2 MB) | inter (128 KB)
    ushort* xb = (ushort*)d_ws;
    ushort* Wb = xb + (size_t)TOKENS * DIN;
    float* inter = (float*)(Wb + (size_t)DOUT * DIN);

    hipLaunchKernelGGL(k_inter_cvt, dim3(1024 + 256), dim3(256), 0, stream,
                       x, Bp, W, inter, xb, Wb);
    hipLaunchKernelGGL(k_gemm_fused, dim3((TOKENS / BM) * (DOUT / BN)), dim3(256), 0, stream,
                       xb, Wb, bias, inter, Ap, out);
}

// Round 15
// 67.743 us; speedup vs baseline: 2.9421x; 1.0363x over previous
//
#include <hip/hip_runtime.h>
#include <hip/hip_bf16.h>
#include <stdint.h>

#define TOKENS 4096
#define DIN 1024
#define DOUT 1024
#define RANK 8
#define BM 128
#define BN 64
#define BK 64

typedef __attribute__((ext_vector_type(4))) float f32x4;
typedef __attribute__((ext_vector_type(8))) short short8;

__device__ __forceinline__ unsigned short f2bf(float f) {
    union { float f; unsigned u; } v; v.f = f;
    unsigned r = v.u + 0x7FFFu + ((v.u >> 16) & 1u);
    return (unsigned short)(r >> 16);
}

__device__ __forceinline__ float dot4(float4 a, float4 b) {
    return a.x * b.x + a.y * b.y + a.z * b.z + a.w * b.w;
}

// Blocks [0,2048): 2 tokens/block, each token split across TWO half-token
// waves (wave = token-half). 8192 waves total -> ~22 waves/CU (vs 16 before),
// each holding 16 independent B-float4s in flight: Little's-law fix for the
// 128 MB B-stream. Blocks [2048,2304): W fp32->bf16.
__global__ __launch_bounds__(256) void k_inter_cvt(const float* __restrict__ x,
                                                   const float* __restrict__ Bp,
                                                   const float* __restrict__ W,
                                                   float* __restrict__ inter,
                                                   ushort* __restrict__ xb,
                                                   ushort* __restrict__ Wb) {
    const int bid = blockIdx.x;
    const int tid = threadIdx.x;

    if (bid >= 2048) {
        const int b2 = bid - 2048;
        const float4* w4 = (const float4*)(W + (size_t)b2 * 4096);
        ushort4* o4 = (ushort4*)(Wb + (size_t)b2 * 4096);
#pragma unroll
        for (int j = 0; j < 4; ++j) {
            float4 v = w4[j * 256 + tid];
            ushort4 u;
            u.x = f2bf(v.x); u.y = f2bf(v.y); u.z = f2bf(v.z); u.w = f2bf(v.w);
            o4[j * 256 + tid] = u;
        }
        return;
    }

    const int lane = tid & 63, wave = tid >> 6;
    const int t = bid * 2 + (wave >> 1);     // token
    const int h = wave & 1;                  // half: elements [h*512, h*512+512)

    // ---- x half -> regs + xb (coalesced f4) ----
    const float4* x4 = (const float4*)(x + (size_t)t * DIN);
    float4 xv0 = x4[h * 128 + lane];
    float4 xv1 = x4[h * 128 + 64 + lane];

    ushort4* xb4 = (ushort4*)(xb + (size_t)t * DIN);
    {
        ushort4 u0, u1;
        u0.x = f2bf(xv0.x); u0.y = f2bf(xv0.y); u0.z = f2bf(xv0.z); u0.w = f2bf(xv0.w);
        u1.x = f2bf(xv1.x); u1.y = f2bf(xv1.y); u1.z = f2bf(xv1.z); u1.w = f2bf(xv1.w);
        xb4[h * 128 + lane] = u0;
        xb4[h * 128 + 64 + lane] = u1;
    }

    // ---- B half-rows: issue all 16 loads, then dot (max in-flight) ----
    const float4* B4 = (const float4*)(Bp + (size_t)t * RANK * DIN);
    float4 bv[RANK][2];
#pragma unroll
    for (int r = 0; r < RANK; ++r) {
        bv[r][0] = B4[r * 256 + h * 128 + lane];
        bv[r][1] = B4[r * 256 + h * 128 + 64 + lane];
    }

    float acc[RANK];
#pragma unroll
    for (int r = 0; r < RANK; ++r)
        acc[r] = dot4(bv[r][0], xv0) + dot4(bv[r][1], xv1);

#pragma unroll
    for (int r = 0; r < RANK; ++r) {
#pragma unroll
        for (int off = 32; off > 0; off >>= 1)
            acc[r] += __shfl_xor(acc[r], off, 64);
    }

    __shared__ float part[4][RANK];
    if (lane == 0) {
#pragma unroll
        for (int r = 0; r < RANK; ++r) part[wave][r] = acc[r];
    }
    __syncthreads();

    // wave0 lanes 0..7 -> token t0; wave1 lanes 0..7 -> token t1
    if ((wave == 0 || wave == 1) && lane < RANK) {
        const int tk = bid * 2 + wave;
        inter[(size_t)tk * RANK + lane] =
            part[wave * 2][lane] + part[wave * 2 + 1][lane];
    }
}

// out[m,o] = bias[o] + Xb@Wb^T (bf16 MFMA) + sum_r inter[m,r]*A[m,o,r]
// UNCHANGED from R14 (counted-vmcnt order-pinned pipeline + T2 swizzle).
__global__ __launch_bounds__(256, 2) void k_gemm_fused(const ushort* __restrict__ Xb,
                                                       const ushort* __restrict__ Wb,
                                                       const float* __restrict__ bias,
                                                       const float* __restrict__ inter,
                                                       const float* __restrict__ Ap,
                                                       float* __restrict__ out) {
    __shared__ ushort As[2][BM * BK];   // 2 x 16 KB
    __shared__ ushort Bs[2][BN * BK];   // 2 x 8 KB
    __shared__ float sInter[BM * 8];    // 4 KB
    __shared__ float sBias[BN];

    const int tid = threadIdx.x;
    const int lane = tid & 63, wave = tid >> 6;
    const int wm = wave >> 1, wn = wave & 1;

    const int bid = blockIdx.x;
    const int swz = (bid & 7) * 64 + (bid >> 3);
    const int M0 = (swz >> 4) * BM;
    const int N0 = (swz & 15) * BN;

    const int col16 = lane & 15;
    const int kg = lane >> 4;
    const int c8 = col16 & 7;

    ((float4*)sInter)[tid] = ((const float4*)(inter + (size_t)M0 * RANK))[tid];
    if (tid < 16) ((float4*)sBias)[tid] = ((const float4*)(bias + N0))[tid];

    const float* Abase = Ap + ((size_t)(M0 + wm * 64 + kg * 4) * DOUT +
                               (N0 + wn * 32 + col16)) * RANK;

    auto stage = [&](int b, int kt) {
#pragma unroll
        for (int st = 0; st < 4; ++st) {
            int flat = st * 256 + tid;
            int row = flat >> 3, ch = flat & 7;
            int chs = ch ^ (row & 7);
            const ushort* g = Xb + (size_t)(M0 + row) * DIN + kt + chs * 8;
            __builtin_amdgcn_global_load_lds(
                (const __attribute__((address_space(1))) void*)g,
                (__attribute__((address_space(3))) void*)(&As[b][flat * 8]), 16, 0, 0);
        }
#pragma unroll
        for (int st = 0; st < 2; ++st) {
            int flat = st * 256 + tid;
            int row = flat >> 3, ch = flat & 7;
            int chs = ch ^ (row & 7);
            const ushort* g = Wb + (size_t)(N0 + row) * DIN + kt + chs * 8;
            __builtin_amdgcn_global_load_lds(
                (const __attribute__((address_space(1))) void*)g,
                (__attribute__((address_space(3))) void*)(&Bs[b][flat * 8]), 16, 0, 0);
        }
    };

    auto aptr = [&](int e) {
        const int nf = e >> 3, mf = (e >> 1) & 3, rg0 = (e & 1) * 2;
        return Abase + ((size_t)(mf * 16 + rg0) * DOUT + nf * 16) * RANK;
    };

    float4 areg[2][4];

    {
        const float* Ae0 = aptr(0);
        areg[0][0] = ((const float4*)Ae0)[0];
        areg[0][1] = ((const float4*)Ae0)[1];
        areg[0][2] = ((const float4*)(Ae0 + (size_t)DOUT * RANK))[0];
        areg[0][3] = ((const float4*)(Ae0 + (size_t)DOUT * RANK))[1];
    }
    __builtin_amdgcn_sched_barrier(0);
    stage(0, 0);

    f32x4 acc[4][2] = {};

#pragma unroll
    for (int t = 0; t < 16; ++t) {
        const int cur = t & 1;

        if (t < 15) {
            const float* Ae0 = aptr(t + 1);
            areg[cur ^ 1][0] = ((const float4*)Ae0)[0];
            areg[cur ^ 1][1] = ((const float4*)Ae0)[1];
            areg[cur ^ 1][2] = ((const float4*)(Ae0 + (size_t)DOUT * RANK))[0];
            areg[cur ^ 1][3] = ((const float4*)(Ae0 + (size_t)DOUT * RANK))[1];
            __builtin_amdgcn_sched_barrier(0);
            stage(cur ^ 1, (t + 1) * BK);
        }

        if (t == 0) {
            asm volatile("s_waitcnt vmcnt(10) lgkmcnt(0)" ::: "memory");
        } else if (t < 15) {
            asm volatile("s_waitcnt vmcnt(10)" ::: "memory");
        } else {
            asm volatile("s_waitcnt vmcnt(0)" ::: "memory");
        }
        __builtin_amdgcn_s_barrier();

#pragma unroll
        for (int ks = 0; ks < 2; ++ks) {
            short8 a[4], b[2];
#pragma unroll
            for (int m4 = 0; m4 < 4; ++m4) {
                const int chs = (ks * 4 + kg) ^ c8;
                a[m4] = *(const short8*)(&As[cur][(wm * 64 + m4 * 16 + col16) * BK + chs * 8]);
            }
#pragma unroll
            for (int n2 = 0; n2 < 2; ++n2) {
                const int chs = (ks * 4 + kg) ^ c8;
                b[n2] = *(const short8*)(&Bs[cur][(wn * 32 + n2 * 16 + col16) * BK + chs * 8]);
            }
#pragma unroll
            for (int m4 = 0; m4 < 4; ++m4)
#pragma unroll
                for (int n2 = 0; n2 < 2; ++n2)
                    acc[m4][n2] = __builtin_amdgcn_mfma_f32_16x16x32_bf16(
                        a[m4], b[n2], acc[m4][n2], 0, 0, 0);
        }

        {
            const int nf = t >> 3, mf = (t >> 1) & 3, rg0 = (t & 1) * 2;
            const int mloc0 = wm * 64 + mf * 16 + kg * 4 + rg0;
            const float4* iv0 = (const float4*)(sInter + mloc0 * 8);
            const float4* iv1 = (const float4*)(sInter + (mloc0 + 1) * 8);
            float4 i00 = iv0[0], i01 = iv0[1], i10 = iv1[0], i11 = iv1[1];
            float4 a00 = areg[cur][0], a01 = areg[cur][1];
            float4 a10 = areg[cur][2], a11 = areg[cur][3];
            float d0 = dot4(a00, i00) + dot4(a01, i01);
            float d1 = dot4(a10, i10) + dot4(a11, i11);
            acc[mf][nf][rg0] += d0;
            acc[mf][nf][rg0 + 1] += d1;
        }

        __builtin_amdgcn_s_barrier();
    }

#pragma unroll
    for (int nf = 0; nf < 2; ++nf) {
        const int oc = wn * 32 + nf * 16 + col16;
        const int o = N0 + oc;
        const float bb = sBias[oc];
#pragma unroll
        for (int mf = 0; mf < 4; ++mf) {
#pragma unroll
            for (int rg = 0; rg < 4; ++rg) {
                const int m = M0 + wm * 64 + mf * 16 + kg * 4 + rg;
                out[(size_t)m * DOUT + o] = acc[mf][nf][rg] + bb;
            }
        }
    }
}

extern "C" void kernel_launch(void* const* d_in, const int* in_sizes, int n_in,
                              void* d_out, int out_size, void* d_ws, size_t ws_size,
                              hipStream_t stream) {
    const float* x    = (const float*)d_in[0];
    const float* Ap   = (const float*)d_in[1];
    const float* Bp   = (const float*)d_in[2];
    const float* W    = (const float*)d_in[3];
    const float* bias = (const float*)d_in[4];
    float* out = (float*)d_out;

    // ws: xb (8 MB) | Wb (2 MB) | inter (128 KB)
    ushort* xb = (ushort*)d_ws;
    ushort* Wb = xb + (size_t)TOKENS * DIN;
    float* inter = (float*)(Wb + (size_t)DOUT * DIN);

    hipLaunchKernelGGL(k_inter_cvt, dim3(2048 + 256), dim3(256), 0, stream,
                       x, Bp, W, inter, xb, Wb);
    hipLaunchKernelGGL(k_gemm_fused, dim3((TOKENS / BM) * (DOUT / BN)), dim3(256), 0, stream,
                       xb, Wb, bias, inter, Ap, out);
}